// Round 19
// baseline (44.050 us; speedup 1.0000x reference)
//
#include <hip/hip_runtime.h>

// Resample 48k -> 10k via MFMA: up=5, down=24, 481-tap FIR.
// y[5k+d] = sum_{c=0..119} Tap[c][d]*x[24k-48+c], Tap[c][d]=5h[24d+480-5c]
// Y(16k x 16, 5 cols used) = A(16x128) * B(128x16), 4x mfma_f32_16x16x32_bf16.
// A[r][c]=bf16(x[24(k0+r)-48+c]): lane fragment = 8 contiguous bf16 = ONE
// ds_read_b128. B constant in 16 VGPRs (prep-packed). C/D: col=l&15 (=d),
// row=(l>>4)*4+reg (=k-local) [m89]. R18 = 43.5us.
//
// R19 deltas (issue-side cuts under the zero-overlap sum model):
//  - staging cvt via v_cvt_pk_bf16_f32 (1 instr / 2 floats; was ~5 VALU/float)
//  - staging thread converts 8 floats -> single ds_write_b128 (204 threads)
//  - double-buffered LDS tile (2x3.3kB) -> ONE barrier per tile (was 2)
//  - __launch_bounds__(256,7) -> ~28 waves/CU

#define NIN    1440000
#define NOUTR  300000
#define NROWS  32
#define KTOT   60000
#define NCHUNK 938               // 64-k tiles per row
#define S      8                 // tiles per block
#define NBX    118               // ceil(938/8)
#define TILE_E 1632              // x-elems per tile
#define TILE_P 1648              // +16 zero pad (A reads c<=127 -> idx<=1639)
#define NT8    204               // staging threads (8 floats each)

typedef __attribute__((ext_vector_type(8))) short short8v;
typedef __attribute__((ext_vector_type(4))) float float4v;

__device__ __forceinline__ unsigned short f2b(float f) {
    unsigned u = __builtin_bit_cast(unsigned, f);
    u += 0x7fff + ((u >> 16) & 1);                 // RNE
    return (unsigned short)(u >> 16);
}

// Bpk[(m*64+l)*8+j] = bf16( Tap[c=32m+8*(l>>4)+j][d=l&15] ), 4KB in ws.
__global__ void prep_taps_kernel(const float* __restrict__ h,
                                 unsigned short* __restrict__ Bpk) {
    int i = blockIdx.x * blockDim.x + threadIdx.x;     // 0..2047
    if (i < 2048) {
        int j = i & 7, l = (i >> 3) & 63, m = i >> 9;
        int d = l & 15, q = l >> 4;
        int c = 32 * m + 8 * q + j;
        int t = 24 * d + 480 - 5 * c;
        float v = (d < 5 && t >= 0 && t <= 480) ? h[t] * 5.0f : 0.0f;
        Bpk[i] = f2b(v);
    }
}

__global__ __launch_bounds__(256, 7) void resample_kernel(
    const float* __restrict__ x, const unsigned short* __restrict__ Bpk,
    float* __restrict__ y)
{
    __shared__ short ldsb[2][TILE_P];              // bf16 bits, double-buffered
    const int tid  = threadIdx.x;
    const int lane = tid & 63;
    const int wv   = tid >> 6;                     // 0..3: 16-k group per wave
    const int row  = blockIdx.y;
    const int cb   = blockIdx.x * S;
    const int n    = min(S, NCHUNK - cb);          // block-uniform, >=1
    const float* __restrict__ xr = x + (size_t)row * NIN;

    // B fragments: 4 global b128 loads (L2-hot 4KB), constant across tiles.
    const short8v B0 = *reinterpret_cast<const short8v*>(Bpk + (0 * 64 + lane) * 8);
    const short8v B1 = *reinterpret_cast<const short8v*>(Bpk + (1 * 64 + lane) * 8);
    const short8v B2 = *reinterpret_cast<const short8v*>(Bpk + (2 * 64 + lane) * 8);
    const short8v B3 = *reinterpret_cast<const short8v*>(Bpk + (3 * 64 + lane) * 8);

    if (tid < 16) {                                // zero pad both buffers once
        ldsb[0][TILE_E + tid] = 0;
        ldsb[1][TILE_E + tid] = 0;
    }

    float4 pa, pb;                                 // staged 8 floats / thread

    auto load_regs = [&](int c) {
        const int g0 = 1536 * c - 48;              // fits int; 16B-aligned
        if (tid < NT8) {
            if (g0 >= 0 && g0 + TILE_E <= NIN) {   // interior fast path
                const float4* __restrict__ p = reinterpret_cast<const float4*>(xr + g0);
                pa = p[2 * tid];
                pb = p[2 * tid + 1];
            } else {                               // first/last tiles only
                float v[8];
                #pragma unroll
                for (int j = 0; j < 8; ++j) {
                    const int g = g0 + 8 * tid + j;
                    v[j] = ((unsigned)g < NIN) ? xr[g] : 0.0f;
                }
                pa = make_float4(v[0], v[1], v[2], v[3]);
                pb = make_float4(v[4], v[5], v[6], v[7]);
            }
        }
    };

    auto write_buf = [&](int b) {                  // 4x cvt_pk + one b128 write
        if (tid < NT8) {
            unsigned r0, r1, r2, r3;
            asm("v_cvt_pk_bf16_f32 %0, %1, %2" : "=v"(r0) : "v"(pa.x), "v"(pa.y));
            asm("v_cvt_pk_bf16_f32 %0, %1, %2" : "=v"(r1) : "v"(pa.z), "v"(pa.w));
            asm("v_cvt_pk_bf16_f32 %0, %1, %2" : "=v"(r2) : "v"(pb.x), "v"(pb.y));
            asm("v_cvt_pk_bf16_f32 %0, %1, %2" : "=v"(r3) : "v"(pb.z), "v"(pb.w));
            *reinterpret_cast<uint4*>(&ldsb[b][8 * tid]) = make_uint4(r0, r1, r2, r3);
        }
    };

    load_regs(cb);
    write_buf(0);
    __syncthreads();

    for (int s = 0; s < n; ++s) {
        if (s + 1 < n) load_regs(cb + s + 1);      // issue early; lands post-compute

        // A fragments: row r=lane&15, K-pos = 32m + 8q + j.
        const int r = lane & 15, q = lane >> 4;
        const short* __restrict__ ap = &ldsb[s & 1][24 * (16 * wv + r) + 8 * q];
        const short8v A0 = *reinterpret_cast<const short8v*>(ap);
        const short8v A1 = *reinterpret_cast<const short8v*>(ap + 32);
        const short8v A2 = *reinterpret_cast<const short8v*>(ap + 64);
        const short8v A3 = *reinterpret_cast<const short8v*>(ap + 96);

        float4v acc = {0.f, 0.f, 0.f, 0.f};
        acc = __builtin_amdgcn_mfma_f32_16x16x32_bf16(A0, B0, acc, 0, 0, 0);
        acc = __builtin_amdgcn_mfma_f32_16x16x32_bf16(A1, B1, acc, 0, 0, 0);
        acc = __builtin_amdgcn_mfma_f32_16x16x32_bf16(A2, B2, acc, 0, 0, 0);
        acc = __builtin_amdgcn_mfma_f32_16x16x32_bf16(A3, B3, acc, 0, 0, 0);

        // C/D: col=lane&15 (=d), row=(lane>>4)*4+j (=k-local).
        const int d = lane & 15;
        if (d < 5) {
            const int kbase = 64 * (cb + s) + 16 * wv + 4 * q;
            float* __restrict__ yr = y + (size_t)row * NOUTR;
            #pragma unroll
            for (int j = 0; j < 4; ++j) {
                const int k = kbase + j;
                if (k < KTOT) yr[5 * (size_t)k + d] = acc[j];
            }
        }

        if (s + 1 < n) write_buf((s + 1) & 1);     // other buffer; no race
        __syncthreads();                           // one barrier per tile
    }
}

extern "C" void kernel_launch(void* const* d_in, const int* in_sizes, int n_in,
                              void* d_out, int out_size, void* d_ws, size_t ws_size,
                              hipStream_t stream) {
    const float* x = (const float*)d_in[0];
    const float* h = (const float*)d_in[1];        // 481 taps
    float* y = (float*)d_out;                      // 32 x 300000 f32
    unsigned short* Bpk = (unsigned short*)d_ws;   // 4KB packed B fragments

    prep_taps_kernel<<<8, 256, 0, stream>>>(h, Bpk);
    dim3 grid(NBX, NROWS);                         // 118 x 32, 256-thr blocks
    resample_kernel<<<grid, 256, 0, stream>>>(x, Bpk, y);
}